// Round 1
// baseline (13039.194 us; speedup 1.0000x reference)
//
#include <hip/hip_runtime.h>
#include <math.h>

#define BB 8
#define TT 64
#define VV 30000
#define EE 256
#define HH 512
#define MM 512
#define UU 32
#define WW 512
#define G3 1536

// workspace offsets (in floats)
#define OFF_WUT   0
#define OFF_WWT   262144
#define OFF_YALL  524288
#define OFF_GIALL 655360
#define OFF_WYALL 1441792
#define OFF_HA    1442304
#define OFF_HB    1446400
#define OFF_HU    1450496
#define OFF_HW    1454592
#define OFF_SW    1458688
#define OFF_CTX   1462784

#define DEC_SZ (BB*TT*VV)
#define SUW_OFF DEC_SZ
#define SU_OFF  (DEC_SZ + BB*TT*WW)

__device__ __forceinline__ float sigm(float x){ return 1.0f/(1.0f+__expf(-x)); }

// ---- precompute kernels ----

__global__ void k_transpose(const float* __restrict__ Wu, const float* __restrict__ Ww,
                            float* __restrict__ ws){
  int idx = blockIdx.x*256 + threadIdx.x;      // 2*512*512
  int which = idx >> 18;
  int rem = idx & 262143;
  int h = rem >> 9, m = rem & 511;
  if (which == 0) ws[OFF_WUT + m*HH + h] = Wu[rem];
  else            ws[OFF_WWT + m*HH + h] = Ww[rem];
}

__global__ void k_gather_y(const int* __restrict__ target, const float* __restrict__ emb,
                           float* __restrict__ ws){
  int idx = blockIdx.x*256 + threadIdx.x;      // B*T*E
  int bt = idx >> 8; int e = idx & 255;
  int tok = target[bt];
  ws[OFF_YALL + idx] = emb[tok*EE + e];
}

__global__ void k_gi(const float* __restrict__ W_ih, const float* __restrict__ b_ih,
                     float* __restrict__ ws){
  int wid  = blockIdx.x*4 + (threadIdx.x>>6);  // B*T*1536 waves
  int lane = threadIdx.x & 63;
  int bt = wid / G3; int j = wid - bt*G3;
  const float* y  = ws + OFF_YALL + bt*EE;
  const float* wr = W_ih + j*EE;
  float acc = 0.f;
  for (int e = lane; e < EE; e += 64) acc += y[e]*wr[e];
  for (int off=32; off; off>>=1) acc += __shfl_xor(acc, off);
  if (lane == 0) ws[OFF_GIALL + bt*G3 + j] = acc + b_ih[j];
}

__global__ void k_wy(const float* __restrict__ Wy, float* __restrict__ ws){
  int wid  = blockIdx.x*4 + (threadIdx.x>>6);  // B*T waves
  int lane = threadIdx.x & 63;
  const float* y = ws + OFF_YALL + wid*EE;
  float acc = 0.f;
  for (int e=lane; e<EE; e+=64) acc += y[e]*Wy[e];
  for (int off=32; off; off>>=1) acc += __shfl_xor(acc, off);
  if (lane == 0) ws[OFF_WYALL + wid] = acc;
}

__global__ void k_h0(const float* __restrict__ u_output, const int* __restrict__ u_len,
                     float* __restrict__ ws){
  int idx = blockIdx.x*256 + threadIdx.x;      // B*H
  int b = idx >> 9; int k = idx & 511;
  int u = u_len[b]-1;
  ws[OFF_HA + idx] = u_output[(b*UU+u)*MM + k];
}

// ---- per-step kernels ----

__global__ void k_gru(const float* __restrict__ W_hh, const float* __restrict__ b_hh,
                      const float* __restrict__ hin, float* __restrict__ hout,
                      const float* __restrict__ gi_all, int t){
  int wid  = blockIdx.x*4 + (threadIdx.x>>6);  // B*H waves
  int lane = threadIdx.x & 63;
  int b = wid >> 9; int k = wid & 511;
  const float* h  = hin + b*HH;
  const float* wr = W_hh + k*HH;
  const float* wz = W_hh + (HH + k)*HH;
  const float* wn = W_hh + (2*HH + k)*HH;
  float pr=0.f, pz=0.f, pn=0.f;
  for (int kk=lane; kk<HH; kk+=64){
    float hv = h[kk];
    pr += hv*wr[kk]; pz += hv*wz[kk]; pn += hv*wn[kk];
  }
  for (int off=32; off; off>>=1){
    pr += __shfl_xor(pr,off); pz += __shfl_xor(pz,off); pn += __shfl_xor(pn,off);
  }
  if (lane == 0){
    const float* gi = gi_all + (b*TT + t)*G3;
    float r = sigm(gi[k]      + pr + b_hh[k]);
    float z = sigm(gi[HH+k]   + pz + b_hh[HH+k]);
    float n = tanhf(gi[2*HH+k] + r*(pn + b_hh[2*HH+k]));
    hout[b*HH+k] = (1.f-z)*n + z*h[k];
  }
}

__global__ void k_hproj(const float* __restrict__ wut, const float* __restrict__ wwt,
                        const float* __restrict__ hnew, float* __restrict__ hU,
                        float* __restrict__ hW){
  int wid  = blockIdx.x*4 + (threadIdx.x>>6);  // 2*B*M waves
  int lane = threadIdx.x & 63;
  int which = wid >> 12;
  int rem = wid & 4095;
  int b = rem >> 9, m = rem & 511;
  const float* src = (which ? wwt : wut) + m*HH;
  const float* h = hnew + b*HH;
  float acc = 0.f;
  for (int k=lane; k<HH; k+=64) acc += h[k]*src[k];
  for (int off=32; off; off>>=1) acc += __shfl_xor(acc, off);
  if (lane == 0) (which ? hW : hU)[rem] = acc;
}

// blocks 0..1023: sw[b,w] dots.  blocks 1024..1031: per-b su softmax + gamma + mix
__global__ void k_scores(const float* __restrict__ u_output, const float* __restrict__ w_output,
                         const int* __restrict__ u_len,
                         const float* __restrict__ Wd, const float* __restrict__ Ws,
                         const float* __restrict__ bs,
                         const float* __restrict__ hnew, const float* __restrict__ hU,
                         const float* __restrict__ hW, const float* __restrict__ wy_all,
                         float* __restrict__ swbuf, float* __restrict__ out, int t){
  if (blockIdx.x < 1024){
    int wid  = blockIdx.x*4 + (threadIdx.x>>6);
    int lane = threadIdx.x & 63;
    int b = wid >> 9, w = wid & 511;
    const float* hw = hW + b*MM;
    const float* wo = w_output + (b*WW + w)*MM;
    float acc = 0.f;
    for (int m=lane; m<MM; m+=64) acc += hw[m]*wo[m];
    for (int off=32; off; off>>=1) acc += __shfl_xor(acc, off);
    if (lane == 0) swbuf[b*WW + w] = acc;
    return;
  }
  int b = blockIdx.x - 1024;
  int tid = threadIdx.x;
  __shared__ float red[256];
  __shared__ float su_s[UU];
  __shared__ float gamma_s;
  // su_raw: 8 threads per u
  {
    int u = tid >> 3, l8 = tid & 7;
    const float* hu = hU + b*MM;
    const float* uo = u_output + (b*UU + u)*MM;
    float acc = 0.f;
    for (int m=l8; m<MM; m+=8) acc += hu[m]*uo[m];
    acc += __shfl_xor(acc,1); acc += __shfl_xor(acc,2); acc += __shfl_xor(acc,4);
    if (l8 == 0) su_s[u] = acc;
  }
  // gamma: d_prev.Wd + h_new.Ws  (wy + bs added later)
  float p1 = 0.f;
  if (t > 0){
    const float* dprev = out + (size_t)(b*TT + (t-1))*VV;
    for (int v=tid; v<VV; v+=256) p1 += dprev[v]*Wd[v];
  }
  {
    const float* h = hnew + b*HH;
    for (int k=tid; k<HH; k+=256) p1 += h[k]*Ws[k];
  }
  red[tid] = p1;
  __syncthreads();
  for (int s=128; s; s>>=1){ if (tid<s) red[tid] += red[tid+s]; __syncthreads(); }
  if (tid == 0) gamma_s = sigm(red[0] + wy_all[b*TT + t] + bs[0]);
  __syncthreads();
  if (tid < 32){
    int ul = u_len[b];
    float g = gamma_s;
    float sv = su_s[tid];
    bool valid = tid < ul;
    float mv = valid ? sv : -1e30f;
    for (int off=16; off; off>>=1) mv = fmaxf(mv, __shfl_xor(mv, off));
    float e = valid ? __expf(sv - mv) : 0.f;
    float ssum = e;
    for (int off=16; off; off>>=1) ssum += __shfl_xor(ssum, off);
    float p = e/ssum;
    float eu = 0.f;
    if (t > 0) eu = out[SU_OFF + (b*TT + (t-1))*UU + tid];
    float mix = (1.f-g)*p + g*eu;
    float s2 = mix;
    for (int off=16; off; off>>=1) s2 += __shfl_xor(s2, off);
    out[SU_OFF + (b*TT + t)*UU + tid] = mix / s2;
  }
}

__global__ void k_ctx(const float* __restrict__ w_output, const int* __restrict__ w_len,
                      const int* __restrict__ word2utt, const float* __restrict__ swbuf,
                      float* __restrict__ ctx, float* __restrict__ out, int t){
  int b = blockIdx.x;
  int tid = threadIdx.x;
  __shared__ float sarr[WW];
  __shared__ int   seg[WW];
  __shared__ float suarr[UU];
  __shared__ float marr[UU], darr[UU];
  __shared__ float suw[WW];
  int wl = w_len[b];
  for (int w=tid; w<WW; w+=256){ sarr[w] = swbuf[b*WW+w]; seg[w] = word2utt[b*WW+w]; }
  if (tid < UU) suarr[tid] = out[SU_OFF + (b*TT+t)*UU + tid];
  __syncthreads();
  {
    int g = tid>>3, l8 = tid&7;
    float mv = -1e30f;
    for (int w=l8; w<wl; w+=8) if (seg[w]==g) mv = fmaxf(mv, sarr[w]);
    mv = fmaxf(mv, __shfl_xor(mv,1)); mv = fmaxf(mv, __shfl_xor(mv,2)); mv = fmaxf(mv, __shfl_xor(mv,4));
    float d = 0.f;
    for (int w=l8; w<wl; w+=8) if (seg[w]==g) d += __expf(sarr[w]-mv);
    d += __shfl_xor(d,1); d += __shfl_xor(d,2); d += __shfl_xor(d,4);
    if (l8 == 0){ marr[g]=mv; darr[g]=d; }
  }
  __syncthreads();
  for (int w=tid; w<WW; w+=256){
    float val = 0.f;
    if (w < wl){ int u = seg[w]; val = suarr[u]*__expf(sarr[w]-marr[u])/darr[u]; }
    suw[w] = val;
    out[SUW_OFF + (b*TT+t)*WW + w] = val;
  }
  __syncthreads();
  float a0=0.f, a1=0.f;
  const float* wo = w_output + (size_t)b*WW*MM;
  for (int w=0; w<wl; ++w){
    float s = suw[w];
    a0 += s*wo[w*MM + tid];
    a1 += s*wo[w*MM + tid + 256];
  }
  ctx[b*MM + tid]       = a0;
  ctx[b*MM + tid + 256] = a1;
}

__global__ void __launch_bounds__(64)
k_logits(const float* __restrict__ Wo, const float* __restrict__ bo,
         const float* __restrict__ ctx, const float* __restrict__ hnew,
         float* __restrict__ out, int t){
  __shared__ float cat[BB*1024];
  int tid = threadIdx.x;
  for (int idx=tid; idx<BB*1024; idx+=64){
    int b = idx>>10, k = idx&1023;
    cat[idx] = (k<512) ? ctx[b*MM + k] : hnew[b*HH + (k-512)];
  }
  __syncthreads();
  int v0 = blockIdx.x*128;
  int v1 = v0 + tid, v2 = v0 + 64 + tid;
  int v1c = v1 < VV ? v1 : VV-1;
  int v2c = v2 < VV ? v2 : VV-1;
  float acc1[BB] = {0,0,0,0,0,0,0,0};
  float acc2[BB] = {0,0,0,0,0,0,0,0};
  const float4* cat4 = reinterpret_cast<const float4*>(cat);
  const float4* w1 = reinterpret_cast<const float4*>(Wo + (size_t)v1c*1024);
  const float4* w2 = reinterpret_cast<const float4*>(Wo + (size_t)v2c*1024);
  for (int k4=0; k4<256; ++k4){
    float4 a = w1[k4];
    float4 c2 = w2[k4];
    #pragma unroll
    for (int b=0; b<BB; ++b){
      float4 c = cat4[b*256 + k4];
      acc1[b] += a.x*c.x  + a.y*c.y  + a.z*c.z  + a.w*c.w;
      acc2[b] += c2.x*c.x + c2.y*c.y + c2.z*c.z + c2.w*c.w;
    }
  }
  if (v1 < VV){
    float bv = bo[v1];
    #pragma unroll
    for (int b=0; b<BB; ++b) out[(size_t)(b*TT+t)*VV + v1] = acc1[b] + bv;
  }
  if (v2 < VV){
    float bv = bo[v2];
    #pragma unroll
    for (int b=0; b<BB; ++b) out[(size_t)(b*TT+t)*VV + v2] = acc2[b] + bv;
  }
}

__global__ void k_lsm(float* __restrict__ out, int t){
  int b = blockIdx.x, tid = threadIdx.x;
  float* x = out + (size_t)(b*TT + t)*VV;
  __shared__ float red[256];
  float m = -1e30f;
  for (int v=tid; v<VV; v+=256) m = fmaxf(m, x[v]);
  red[tid] = m; __syncthreads();
  for (int s=128; s; s>>=1){ if (tid<s) red[tid] = fmaxf(red[tid], red[tid+s]); __syncthreads(); }
  float mm = red[0];
  __syncthreads();
  float ssum = 0.f;
  for (int v=tid; v<VV; v+=256) ssum += __expf(x[v]-mm);
  red[tid] = ssum; __syncthreads();
  for (int s=128; s; s>>=1){ if (tid<s) red[tid] += red[tid+s]; __syncthreads(); }
  float lse = mm + logf(red[0]);
  for (int v=tid; v<VV; v+=256) x[v] -= lse;
}

extern "C" void kernel_launch(void* const* d_in, const int* in_sizes, int n_in,
                              void* d_out, int out_size, void* d_ws, size_t ws_size,
                              hipStream_t stream) {
  const int*   target   = (const int*)d_in[0];
  const float* u_output = (const float*)d_in[1];
  const float* w_output = (const float*)d_in[2];
  const int*   u_len    = (const int*)d_in[3];
  const int*   w_len    = (const int*)d_in[4];
  const int*   word2utt = (const int*)d_in[5];
  const float* emb      = (const float*)d_in[6];
  const float* W_ih     = (const float*)d_in[7];
  const float* W_hh     = (const float*)d_in[8];
  const float* b_ih     = (const float*)d_in[9];
  const float* b_hh     = (const float*)d_in[10];
  const float* Wu       = (const float*)d_in[11];
  const float* Ww       = (const float*)d_in[13];
  const float* Wo       = (const float*)d_in[15];
  const float* bo       = (const float*)d_in[16];
  const float* Wd       = (const float*)d_in[17];
  const float* Wy       = (const float*)d_in[18];
  const float* Ws       = (const float*)d_in[19];
  const float* bs       = (const float*)d_in[20];
  float* out = (float*)d_out;
  float* ws  = (float*)d_ws;

  hipLaunchKernelGGL(k_transpose, dim3(2048), dim3(256), 0, stream, Wu, Ww, ws);
  hipLaunchKernelGGL(k_gather_y,  dim3(512),  dim3(256), 0, stream, target, emb, ws);
  hipLaunchKernelGGL(k_gi,        dim3(196608), dim3(256), 0, stream, W_ih, b_ih, ws);
  hipLaunchKernelGGL(k_wy,        dim3(128),  dim3(256), 0, stream, Wy, ws);
  hipLaunchKernelGGL(k_h0,        dim3(16),   dim3(256), 0, stream, u_output, u_len, ws);

  for (int t=0; t<TT; ++t){
    float* hin  = ws + ((t & 1) == 0 ? OFF_HA : OFF_HB);
    float* hout = ws + ((t & 1) == 0 ? OFF_HB : OFF_HA);
    hipLaunchKernelGGL(k_gru,   dim3(1024), dim3(256), 0, stream,
                       W_hh, b_hh, hin, hout, ws+OFF_GIALL, t);
    hipLaunchKernelGGL(k_hproj, dim3(2048), dim3(256), 0, stream,
                       ws+OFF_WUT, ws+OFF_WWT, hout, ws+OFF_HU, ws+OFF_HW);
    hipLaunchKernelGGL(k_scores, dim3(1032), dim3(256), 0, stream,
                       u_output, w_output, u_len, Wd, Ws, bs,
                       hout, ws+OFF_HU, ws+OFF_HW, ws+OFF_WYALL, ws+OFF_SW, out, t);
    hipLaunchKernelGGL(k_ctx,   dim3(8), dim3(256), 0, stream,
                       w_output, w_len, word2utt, ws+OFF_SW, ws+OFF_CTX, out, t);
    hipLaunchKernelGGL(k_logits, dim3(235), dim3(64), 0, stream,
                       Wo, bo, ws+OFF_CTX, hout, out, t);
    hipLaunchKernelGGL(k_lsm,   dim3(8), dim3(256), 0, stream, out, t);
  }
}

// Round 2
// 6098.543 us; speedup vs baseline: 2.1381x; 2.1381x over previous
//
#include <hip/hip_runtime.h>
#include <math.h>

typedef unsigned short ushort_t;
typedef unsigned int uint_t;

#define BB 8
#define TT 64
#define VV 30000
#define VP 30080
#define EE 256
#define HH 512
#define MM 512
#define UU 32
#define WW 512
#define G3 1536
#define NLB 235
#define NCH 30

// workspace offsets (floats)
#define OFF_AU    0                       // 8*32*512      = 131072
#define OFF_AW    131072                  // 8*512*512     = 2097152
#define OFF_YALL  2228224                 // 512*256       = 131072
#define OFF_GI    2359296                 // 512*1536      = 786432
#define OFF_WY    3145728                 // 512
#define OFF_HA    3146240                 // 4096
#define OFF_HB    3150336                 // 4096
#define OFF_SW    3154432                 // 4096
#define OFF_CATT  3158528                 // 1024*8 = 8192
#define OFF_PDWD  3166720                 // 240 (pad 256)
#define OFF_PART  3166976                 // 235*16 = 3760 (pad)
#define OFF_WOT   3170816                 // bf16 1024*30080
#define WS_NEED_PRIMARY (3170816ULL*4ULL + 1024ULL*VP*2ULL)
#define WS_NEED_FB      (3170816ULL*4ULL)

#define DEC_SZ (BB*TT*VV)
#define SUW_OFF DEC_SZ
#define SU_OFF  (DEC_SZ + BB*TT*WW)

__device__ __forceinline__ float sigm(float x){ return 1.0f/(1.0f+__expf(-x)); }

// ---------------- precompute ----------------

// C[M,N] = A[M,K] @ B[N,K]^T (+bias[N]).  M,N mult of 64, K mult of 32.
__global__ void __launch_bounds__(256)
k_gemm_nt(const float* __restrict__ A, const float* __restrict__ B,
          const float* __restrict__ bias, float* __restrict__ C,
          int M, int N, int K){
  __shared__ float As[32][65];
  __shared__ float Bs[32][65];
  int tid = threadIdx.x;
  int bx = blockIdx.x, by = blockIdx.y;
  int tx = tid & 15, ty = tid >> 4;
  float acc[4][4] = {};
  int r = tid >> 2, cbase = (tid & 3) * 8;
  for (int k0 = 0; k0 < K; k0 += 32){
    const float* ap = A + (size_t)(by*64 + r)*K + k0 + cbase;
    const float* bp = B + (size_t)(bx*64 + r)*K + k0 + cbase;
    #pragma unroll
    for (int i=0;i<8;++i) As[cbase+i][r] = ap[i];
    #pragma unroll
    for (int i=0;i<8;++i) Bs[cbase+i][r] = bp[i];
    __syncthreads();
    #pragma unroll
    for (int kk=0;kk<32;++kk){
      float a0=As[kk][ty*4+0], a1=As[kk][ty*4+1], a2=As[kk][ty*4+2], a3=As[kk][ty*4+3];
      float b0=Bs[kk][tx*4+0], b1=Bs[kk][tx*4+1], b2=Bs[kk][tx*4+2], b3=Bs[kk][tx*4+3];
      acc[0][0]+=a0*b0; acc[0][1]+=a0*b1; acc[0][2]+=a0*b2; acc[0][3]+=a0*b3;
      acc[1][0]+=a1*b0; acc[1][1]+=a1*b1; acc[1][2]+=a1*b2; acc[1][3]+=a1*b3;
      acc[2][0]+=a2*b0; acc[2][1]+=a2*b1; acc[2][2]+=a2*b2; acc[2][3]+=a2*b3;
      acc[3][0]+=a3*b0; acc[3][1]+=a3*b1; acc[3][2]+=a3*b2; acc[3][3]+=a3*b3;
    }
    __syncthreads();
  }
  #pragma unroll
  for (int i=0;i<4;++i){
    int row = by*64 + ty*4 + i;
    #pragma unroll
    for (int j=0;j<4;++j){
      int col = bx*64 + tx*4 + j;
      float v = acc[i][j];
      if (bias) v += bias[col];
      C[(size_t)row*N + col] = v;
    }
  }
}

__global__ void k_gather_y(const int* __restrict__ target, const float* __restrict__ emb,
                           float* __restrict__ ws){
  int idx = blockIdx.x*256 + threadIdx.x;   // B*T*E
  int bt = idx >> 8; int e = idx & 255;
  int tok = target[bt];
  ws[OFF_YALL + idx] = emb[tok*EE + e];
}

__global__ void k_wy(const float* __restrict__ Wy, float* __restrict__ ws){
  int wid  = blockIdx.x*4 + (threadIdx.x>>6); // B*T waves
  int lane = threadIdx.x & 63;
  const float* y = ws + OFF_YALL + wid*EE;
  float acc = 0.f;
  for (int e=lane; e<EE; e+=64) acc += y[e]*Wy[e];
  for (int off=32; off; off>>=1) acc += __shfl_xor(acc, off);
  if (lane == 0) ws[OFF_WY + wid] = acc;
}

__global__ void k_h0(const float* __restrict__ u_output, const int* __restrict__ u_len,
                     float* __restrict__ ws){
  int idx = blockIdx.x*256 + threadIdx.x;   // B*H
  int b = idx >> 9; int k = idx & 511;
  int u = u_len[b]-1;
  ws[OFF_HA + idx] = u_output[(b*UU+u)*MM + k];
}

// WoT[k][v] = bf16(Wo[v][k]); v >= VV padded with 0.
__global__ void __launch_bounds__(256)
k_woT(const float* __restrict__ Wo, ushort_t* __restrict__ wt){
  __shared__ float tile[64][65];
  int v0 = blockIdx.x * 64;   // VP/64 = 470
  int k0 = blockIdx.y * 64;   // 16
  int tid = threadIdx.x;
  int r = tid >> 2, c4 = (tid & 3) * 16;
  int v = v0 + r;
  if (v < VV){
    const float* src = Wo + (size_t)v*1024 + k0 + c4;
    #pragma unroll
    for (int i=0;i<16;i+=4){
      float4 f = *(const float4*)(src + i);
      tile[r][c4+i]=f.x; tile[r][c4+i+1]=f.y; tile[r][c4+i+2]=f.z; tile[r][c4+i+3]=f.w;
    }
  } else {
    #pragma unroll
    for (int i=0;i<16;++i) tile[r][c4+i]=0.f;
  }
  __syncthreads();
  int vv = tid & 63; int kkb = (tid >> 6) * 16;
  #pragma unroll
  for (int i=0;i<16;++i){
    int kk = kkb + i;
    uint_t u = __float_as_uint(tile[vv][kk]);
    uint_t r16 = (u + 0x7fffu + ((u>>16)&1u)) >> 16;
    wt[(size_t)(k0+kk)*VP + v0 + vv] = (ushort_t)r16;
  }
}

// ---------------- per-step ----------------

__global__ void k_gru(const float* __restrict__ W_hh, const float* __restrict__ b_hh,
                      const float* __restrict__ hin, float* __restrict__ hout,
                      const float* __restrict__ gi_all, float* __restrict__ catT, int t){
  int wid  = blockIdx.x*4 + (threadIdx.x>>6);  // B*H waves
  int lane = threadIdx.x & 63;
  int b = wid >> 9; int k = wid & 511;
  const float* h  = hin + b*HH;
  const float* wr = W_hh + k*HH;
  const float* wz = W_hh + (HH + k)*HH;
  const float* wn = W_hh + (2*HH + k)*HH;
  float pr=0.f, pz=0.f, pn=0.f;
  for (int kk=lane; kk<HH; kk+=64){
    float hv = h[kk];
    pr += hv*wr[kk]; pz += hv*wz[kk]; pn += hv*wn[kk];
  }
  for (int off=32; off; off>>=1){
    pr += __shfl_xor(pr,off); pz += __shfl_xor(pz,off); pn += __shfl_xor(pn,off);
  }
  if (lane == 0){
    const float* gi = gi_all + (b*TT + t)*G3;
    float r = sigm(gi[k]      + pr + b_hh[k]);
    float z = sigm(gi[HH+k]   + pz + b_hh[HH+k]);
    float n = tanhf(gi[2*HH+k] + r*(pn + b_hh[2*HH+k]));
    float hv = (1.f-z)*n + z*h[k];
    hout[b*HH+k] = hv;
    catT[(512+k)*8 + b] = hv;
  }
}

// blocks 0..1023: sw[b,w] = h . Aw[b,w,:].  blocks 1024..1031: su softmax + gamma + mix
__global__ void k_att(const float* __restrict__ Au, const float* __restrict__ Aw,
                      const int* __restrict__ u_len,
                      const float* __restrict__ Ws, const float* __restrict__ bs,
                      const float* __restrict__ hnew, const float* __restrict__ wy_all,
                      const float* __restrict__ pdwd,
                      float* __restrict__ swbuf, float* __restrict__ out, int t){
  if (blockIdx.x < 1024){
    int wid  = blockIdx.x*4 + (threadIdx.x>>6);
    int lane = threadIdx.x & 63;
    int b = wid >> 9, w = wid & 511;
    const float* h  = hnew + b*HH;
    const float* aw = Aw + (size_t)(b*WW + w)*HH;
    float acc = 0.f;
    for (int m=lane; m<HH; m+=64) acc += h[m]*aw[m];
    for (int off=32; off; off>>=1) acc += __shfl_xor(acc, off);
    if (lane == 0) swbuf[b*WW + w] = acc;
    return;
  }
  int b = blockIdx.x - 1024;
  int tid = threadIdx.x;
  __shared__ float red[256];
  __shared__ float su_s[UU];
  __shared__ float gamma_s;
  {
    int u = tid >> 3, l8 = tid & 7;
    const float* h  = hnew + b*HH;
    const float* au = Au + (size_t)(b*UU + u)*HH;
    float acc = 0.f;
    for (int m=l8; m<HH; m+=8) acc += h[m]*au[m];
    acc += __shfl_xor(acc,1); acc += __shfl_xor(acc,2); acc += __shfl_xor(acc,4);
    if (l8 == 0) su_s[u] = acc;
  }
  float p1 = 0.f;
  {
    const float* h = hnew + b*HH;
    for (int k=tid; k<HH; k+=256) p1 += h[k]*Ws[k];
  }
  if (t > 0 && tid < NCH) p1 += pdwd[b*NCH + tid];
  red[tid] = p1;
  __syncthreads();
  for (int s=128; s; s>>=1){ if (tid<s) red[tid] += red[tid+s]; __syncthreads(); }
  if (tid == 0) gamma_s = sigm(red[0] + wy_all[b*TT + t] + bs[0]);
  __syncthreads();
  if (tid < 32){
    int ul = u_len[b];
    float g = gamma_s;
    float sv = su_s[tid];
    bool valid = tid < ul;
    float mv = valid ? sv : -1e30f;
    for (int off=16; off; off>>=1) mv = fmaxf(mv, __shfl_xor(mv, off));
    float e = valid ? __expf(sv - mv) : 0.f;
    float ssum = e;
    for (int off=16; off; off>>=1) ssum += __shfl_xor(ssum, off);
    float p = e/ssum;
    float eu = 0.f;
    if (t > 0) eu = out[SU_OFF + (b*TT + (t-1))*UU + tid];
    float mix = (1.f-g)*p + g*eu;
    float s2 = mix;
    for (int off=16; off; off>>=1) s2 += __shfl_xor(s2, off);
    out[SU_OFF + (b*TT + t)*UU + tid] = mix / s2;
  }
}

__global__ void k_ctx(const float* __restrict__ w_output, const int* __restrict__ w_len,
                      const int* __restrict__ word2utt, const float* __restrict__ swbuf,
                      float* __restrict__ catT, float* __restrict__ out, int t){
  int b = blockIdx.x;
  int tid = threadIdx.x;
  __shared__ float sarr[WW];
  __shared__ int   seg[WW];
  __shared__ float suarr[UU];
  __shared__ float marr[UU], darr[UU];
  __shared__ float suw[WW];
  int wl = w_len[b];
  for (int w=tid; w<WW; w+=256){ sarr[w] = swbuf[b*WW+w]; seg[w] = word2utt[b*WW+w]; }
  if (tid < UU) suarr[tid] = out[SU_OFF + (b*TT+t)*UU + tid];
  __syncthreads();
  {
    int g = tid>>3, l8 = tid&7;
    float mv = -1e30f;
    for (int w=l8; w<wl; w+=8) if (seg[w]==g) mv = fmaxf(mv, sarr[w]);
    mv = fmaxf(mv, __shfl_xor(mv,1)); mv = fmaxf(mv, __shfl_xor(mv,2)); mv = fmaxf(mv, __shfl_xor(mv,4));
    float d = 0.f;
    for (int w=l8; w<wl; w+=8) if (seg[w]==g) d += __expf(sarr[w]-mv);
    d += __shfl_xor(d,1); d += __shfl_xor(d,2); d += __shfl_xor(d,4);
    if (l8 == 0){ marr[g]=mv; darr[g]=d; }
  }
  __syncthreads();
  for (int w=tid; w<WW; w+=256){
    float val = 0.f;
    if (w < wl){ int u = seg[w]; val = suarr[u]*__expf(sarr[w]-marr[u])/darr[u]; }
    suw[w] = val;
    out[SUW_OFF + (b*TT+t)*WW + w] = val;
  }
  __syncthreads();
  float a0=0.f, a1=0.f;
  const float* wo = w_output + (size_t)b*WW*MM;
  for (int w=0; w<wl; ++w){
    float s = suw[w];
    a0 += s*wo[w*MM + tid];
    a1 += s*wo[w*MM + tid + 256];
  }
  catT[tid*8 + b]       = a0;
  catT[(tid+256)*8 + b] = a1;
}

// MODE 0: bf16 WoT [1024][VP]; MODE 1: fp32 Wo [VV][1024] rows.
// grid NLB blocks x 256 thr: block covers 128 v, 4 waves = K quarters.
template<int MODE>
__global__ void __launch_bounds__(256)
k_logits(const ushort_t* __restrict__ wt, const float* __restrict__ Wo,
         const float* __restrict__ bo, const float* __restrict__ catT,
         float* __restrict__ out, float* __restrict__ part, int t){
  int tid = threadIdx.x;
  int kq = tid >> 6, vl = tid & 63;
  int v0 = blockIdx.x * 128;
  int v = v0 + 2*vl;
  float acc0[8] = {0,0,0,0,0,0,0,0};
  float acc1[8] = {0,0,0,0,0,0,0,0};
  const float* cp = catT + kq*256*8;
  if (MODE == 0){
    const ushort_t* wp = wt + (size_t)(kq*256)*VP + v;
    #pragma unroll 8
    for (int k=0;k<256;++k){
      uint_t w2 = *(const uint_t*)(wp); wp += VP;
      float w0 = __uint_as_float((w2 & 0xffffu) << 16);
      float w1 = __uint_as_float((w2 >> 16) << 16);
      float c[8];
      #pragma unroll
      for (int b=0;b<8;++b) c[b] = cp[k*8+b];
      #pragma unroll
      for (int b=0;b<8;++b){ acc0[b] += w0*c[b]; acc1[b] += w1*c[b]; }
    }
  } else {
    int vr0 = (v   < VV) ? v   : 0;
    int vr1 = (v+1 < VV) ? v+1 : 0;
    const float* r0 = Wo + (size_t)vr0*1024 + kq*256;
    const float* r1 = Wo + (size_t)vr1*1024 + kq*256;
    #pragma unroll 4
    for (int k=0;k<256;++k){
      float w0 = r0[k], w1 = r1[k];
      float c[8];
      #pragma unroll
      for (int b=0;b<8;++b) c[b] = cp[k*8+b];
      #pragma unroll
      for (int b=0;b<8;++b){ acc0[b] += w0*c[b]; acc1[b] += w1*c[b]; }
    }
  }
  __shared__ float partial[4][128][8];
  #pragma unroll
  for (int b=0;b<8;++b){
    partial[kq][2*vl][b]   = acc0[b];
    partial[kq][2*vl+1][b] = acc1[b];
  }
  __syncthreads();
  __shared__ float fin[128][8];
  for (int o = tid; o < 1024; o += 256){
    int vv = o >> 3, b = o & 7;
    int gv = v0 + vv;
    float s = partial[0][vv][b]+partial[1][vv][b]+partial[2][vv][b]+partial[3][vv][b];
    float logit = -1e30f;
    if (gv < VV){
      logit = s + bo[gv];
      out[(size_t)(b*TT+t)*VV + gv] = logit;
    }
    fin[vv][b] = logit;
  }
  __syncthreads();
  int b = tid >> 5;
  int l = tid & 31;
  float m = -1e30f;
  for (int vv=l; vv<128; vv+=32) m = fmaxf(m, fin[vv][b]);
  for (int off=16; off; off>>=1) m = fmaxf(m, __shfl_xor(m, off));
  float s = 0.f;
  for (int vv=l; vv<128; vv+=32) s += __expf(fin[vv][b] - m);
  for (int off=16; off; off>>=1) s += __shfl_xor(s, off);
  if (l == 0){ part[blockIdx.x*16 + b*2] = m; part[blockIdx.x*16 + b*2 + 1] = s; }
}

// combine partials -> lse; out -= lse; pdwd[b][ch] = sum (out * Wd) over chunk
__global__ void k_sub(const float* __restrict__ part, const float* __restrict__ Wd,
                      float* __restrict__ out, float* __restrict__ pdwd, int t){
  int b = blockIdx.x / NCH, ch = blockIdx.x % NCH;
  int tid = threadIdx.x;
  __shared__ float sm[256], ss[256];
  float m = -1e30f, s = 0.f;
  if (tid < NLB){ m = part[tid*16 + b*2]; s = part[tid*16 + b*2 + 1]; }
  sm[tid]=m; ss[tid]=s; __syncthreads();
  for (int st=128; st; st>>=1){
    if (tid < st){
      float m1 = sm[tid], s1 = ss[tid];
      float m2 = sm[tid+st], s2 = ss[tid+st];
      float mm = fmaxf(m1, m2);
      ss[tid] = s1*__expf(m1-mm) + s2*__expf(m2-mm);
      sm[tid] = mm;
    }
    __syncthreads();
  }
  float lse = sm[0] + logf(ss[0]);
  __syncthreads();
  float* row = out + (size_t)(b*TT+t)*VV;
  int vstart = ch*1000;
  float p = 0.f;
  for (int v = vstart + tid; v < vstart + 1000; v += 256){
    float x = row[v] - lse;
    row[v] = x;
    p += x * Wd[v];
  }
  sm[tid] = p; __syncthreads();
  for (int st=128; st; st>>=1){ if (tid<st) sm[tid]+=sm[tid+st]; __syncthreads(); }
  if (tid==0) pdwd[b*NCH + ch] = sm[0];
}

extern "C" void kernel_launch(void* const* d_in, const int* in_sizes, int n_in,
                              void* d_out, int out_size, void* d_ws, size_t ws_size,
                              hipStream_t stream) {
  const int*   target   = (const int*)d_in[0];
  const float* u_output = (const float*)d_in[1];
  const float* w_output = (const float*)d_in[2];
  const int*   u_len    = (const int*)d_in[3];
  const int*   w_len    = (const int*)d_in[4];
  const int*   word2utt = (const int*)d_in[5];
  const float* emb      = (const float*)d_in[6];
  const float* W_ih     = (const float*)d_in[7];
  const float* W_hh     = (const float*)d_in[8];
  const float* b_ih     = (const float*)d_in[9];
  const float* b_hh     = (const float*)d_in[10];
  const float* Wu       = (const float*)d_in[11];
  const float* Ww       = (const float*)d_in[13];
  const float* Wo       = (const float*)d_in[15];
  const float* bo       = (const float*)d_in[16];
  const float* Wd       = (const float*)d_in[17];
  const float* Wy       = (const float*)d_in[18];
  const float* Ws       = (const float*)d_in[19];
  const float* bs       = (const float*)d_in[20];
  float* out = (float*)d_out;
  float* ws  = (float*)d_ws;
  ushort_t* wt = (ushort_t*)(ws + OFF_WOT);
  bool primary = ws_size >= WS_NEED_PRIMARY;

  hipLaunchKernelGGL(k_gather_y, dim3(512), dim3(256), 0, stream, target, emb, ws);
  // gi = yall @ W_ih^T + b_ih : M=512 N=1536 K=256
  hipLaunchKernelGGL(k_gemm_nt, dim3(24,8), dim3(256), 0, stream,
                     ws+OFF_YALL, W_ih, b_ih, ws+OFF_GI, 512, 1536, 256);
  // Au = u_output @ Wu^T : M=256 N=512 K=512 (bias cancels in softmax)
  hipLaunchKernelGGL(k_gemm_nt, dim3(8,4), dim3(256), 0, stream,
                     u_output, Wu, (const float*)nullptr, ws+OFF_AU, 256, 512, 512);
  // Aw = w_output @ Ww^T : M=4096 N=512 K=512
  hipLaunchKernelGGL(k_gemm_nt, dim3(8,64), dim3(256), 0, stream,
                     w_output, Ww, (const float*)nullptr, ws+OFF_AW, 4096, 512, 512);
  hipLaunchKernelGGL(k_wy, dim3(128), dim3(256), 0, stream, Wy, ws);
  hipLaunchKernelGGL(k_h0, dim3(16), dim3(256), 0, stream, u_output, u_len, ws);
  if (primary)
    hipLaunchKernelGGL(k_woT, dim3(VP/64,16), dim3(256), 0, stream, Wo, wt);

  for (int t=0; t<TT; ++t){
    float* hin  = ws + ((t & 1) == 0 ? OFF_HA : OFF_HB);
    float* hout = ws + ((t & 1) == 0 ? OFF_HB : OFF_HA);
    hipLaunchKernelGGL(k_gru, dim3(1024), dim3(256), 0, stream,
                       W_hh, b_hh, hin, hout, ws+OFF_GI, ws+OFF_CATT, t);
    hipLaunchKernelGGL(k_att, dim3(1032), dim3(256), 0, stream,
                       ws+OFF_AU, ws+OFF_AW, u_len, Ws, bs,
                       hout, ws+OFF_WY, ws+OFF_PDWD, ws+OFF_SW, out, t);
    hipLaunchKernelGGL(k_ctx, dim3(8), dim3(256), 0, stream,
                       w_output, w_len, word2utt, ws+OFF_SW, ws+OFF_CATT, out, t);
    if (primary)
      k_logits<0><<<dim3(NLB), dim3(256), 0, stream>>>(wt, Wo, bo, ws+OFF_CATT, out, ws+OFF_PART, t);
    else
      k_logits<1><<<dim3(NLB), dim3(256), 0, stream>>>(wt, Wo, bo, ws+OFF_CATT, out, ws+OFF_PART, t);
    hipLaunchKernelGGL(k_sub, dim3(BB*NCH), dim3(256), 0, stream,
                       ws+OFF_PART, Wd, out, ws+OFF_PDWD, t);
  }
}

// Round 3
// 2865.538 us; speedup vs baseline: 4.5503x; 2.1282x over previous
//
#include <hip/hip_runtime.h>
#include <math.h>

typedef unsigned short ushort_t;
typedef unsigned int uint_t;

#define BB 8
#define TT 64
#define VV 30000
#define VP 30080
#define EE 256
#define HH 512
#define MM 512
#define UU 32
#define WW 512
#define G3 1536
#define NLB 235

// workspace offsets (floats)
#define OFF_GI    0          // 512*1536
#define OFF_YALL  786432     // 512*256
#define OFF_WY    917504     // 512
#define OFF_H0    918016     // 4096
#define OFF_HALL  922112     // 512*512
#define OFF_HU    1184256    // 512*512
#define OFF_HW    1446400    // 512*512
#define OFF_HS    1708544    // 512
#define OFF_HWV   1709056    // 512
#define OFF_P     1709568    // 64*8*32
#define OFF_SW    1725952    // 64*8*512  (sw -> pw in place)
#define OFF_C     1988096    // bf16 64*8*32*512 elems = 4194304 float slots
#define OFF_E     6182400    // 16384
#define OFF_WV    6198784    // 1024 + 2 (s_bo, s_wd), pad 1536
#define OFF_CTXT  6200320    // 512*8
#define OFF_PART  6204416    // 235*16 pad 4096
#define OFF_SUBUF 6208512    // 256
#define OFF_QBUF  6208768    // 64
#define OFF_LSE   6208832    // 512
#define OFF_WOTC  6209344    // bf16 512*30080 elems = 7700480 float slots
// total 13909824 floats = 55.6 MB

#define DEC_SZ (BB*TT*VV)
#define SUW_OFF DEC_SZ
#define SU_OFF  (DEC_SZ + BB*TT*WW)

__device__ __forceinline__ float sigm(float x){ return 1.0f/(1.0f+__expf(-x)); }
__device__ __forceinline__ ushort_t to_bf16(float f){
  uint_t u = __float_as_uint(f);
  return (ushort_t)((u + 0x7fffu + ((u>>16)&1u)) >> 16);
}
__device__ __forceinline__ float from_bf16(ushort_t s){
  return __uint_as_float(((uint_t)s) << 16);
}

// ---------------- precompute ----------------

// C[row,col] = sum_k A[row,k]*B'[k,col] (+bias[col]); TRANSB=1: B'[k,col]=B[col,k]
template<int TRANSB>
__global__ void __launch_bounds__(256)
k_gemm_b(const float* __restrict__ A, int lda, int aS,
         const float* __restrict__ B, int ldb, int bS,
         const float* __restrict__ bias,
         float* __restrict__ C, int ldc, int cS, int K){
  A += (size_t)blockIdx.z * aS;
  B += (size_t)blockIdx.z * bS;
  C += (size_t)blockIdx.z * cS;
  __shared__ float As[32][65];
  __shared__ float Bs[32][65];
  int tid = threadIdx.x;
  int bx = blockIdx.x, by = blockIdx.y;
  int tx = tid & 15, ty = tid >> 4;
  float acc[4][4] = {};
  for (int k0 = 0; k0 < K; k0 += 32){
    {
      int r = tid >> 2, cbase = (tid & 3) * 8;
      const float* ap = A + (size_t)(by*64 + r)*lda + k0 + cbase;
      #pragma unroll
      for (int i=0;i<8;++i) As[cbase+i][r] = ap[i];
    }
    if (TRANSB){
      int r = tid >> 2, cbase = (tid & 3) * 8;
      const float* bp = B + (size_t)(bx*64 + r)*ldb + k0 + cbase;
      #pragma unroll
      for (int i=0;i<8;++i) Bs[cbase+i][r] = bp[i];
    } else {
      int kk = tid >> 3, cbase = (tid & 7) * 8;
      const float* bp = B + (size_t)(k0 + kk)*ldb + bx*64 + cbase;
      #pragma unroll
      for (int i=0;i<8;++i) Bs[kk][cbase+i] = bp[i];
    }
    __syncthreads();
    #pragma unroll
    for (int kk=0;kk<32;++kk){
      float a0=As[kk][ty*4+0], a1=As[kk][ty*4+1], a2=As[kk][ty*4+2], a3=As[kk][ty*4+3];
      float b0=Bs[kk][tx*4+0], b1=Bs[kk][tx*4+1], b2=Bs[kk][tx*4+2], b3=Bs[kk][tx*4+3];
      acc[0][0]+=a0*b0; acc[0][1]+=a0*b1; acc[0][2]+=a0*b2; acc[0][3]+=a0*b3;
      acc[1][0]+=a1*b0; acc[1][1]+=a1*b1; acc[1][2]+=a1*b2; acc[1][3]+=a1*b3;
      acc[2][0]+=a2*b0; acc[2][1]+=a2*b1; acc[2][2]+=a2*b2; acc[2][3]+=a2*b3;
      acc[3][0]+=a3*b0; acc[3][1]+=a3*b1; acc[3][2]+=a3*b2; acc[3][3]+=a3*b3;
    }
    __syncthreads();
  }
  #pragma unroll
  for (int i=0;i<4;++i){
    int row = by*64 + ty*4 + i;
    #pragma unroll
    for (int j=0;j<4;++j){
      int col = bx*64 + tx*4 + j;
      float v = acc[i][j];
      if (bias) v += bias[col];
      C[(size_t)row*ldc + col] = v;
    }
  }
}

__global__ void k_gather_y(const int* __restrict__ target, const float* __restrict__ emb,
                           float* __restrict__ ws){
  int idx = blockIdx.x*256 + threadIdx.x;   // B*T*E
  int bt = idx >> 8; int e = idx & 255;
  int tok = target[bt];
  ws[OFF_YALL + idx] = emb[tok*EE + e];
}

__global__ void k_wy(const float* __restrict__ Wy, float* __restrict__ ws){
  int wid  = blockIdx.x*4 + (threadIdx.x>>6); // B*T waves
  int lane = threadIdx.x & 63;
  const float* y = ws + OFF_YALL + wid*EE;
  float acc = 0.f;
  for (int e=lane; e<EE; e+=64) acc += y[e]*Wy[e];
  for (int off=32; off; off>>=1) acc += __shfl_xor(acc, off);
  if (lane == 0) ws[OFF_WY + wid] = acc;
}

__global__ void k_h0(const float* __restrict__ u_output, const int* __restrict__ u_len,
                     float* __restrict__ ws){
  int idx = blockIdx.x*256 + threadIdx.x;   // B*H
  int b = idx >> 9; int k = idx & 511;
  int u = u_len[b]-1;
  ws[OFF_H0 + idx] = u_output[(b*UU+u)*MM + k];
}

// WOTC[k][v] = bf16(Wo[v][k]) for k<512 (ctx half)
__global__ void __launch_bounds__(256)
k_woTc(const float* __restrict__ Wo, ushort_t* __restrict__ wt){
  __shared__ float tile[64][65];
  int v0 = blockIdx.x * 64;   // 470
  int k0 = blockIdx.y * 64;   // 8
  int tid = threadIdx.x;
  int r = tid >> 2, c4 = (tid & 3) * 16;
  int v = v0 + r;
  if (v < VV){
    const float* src = Wo + (size_t)v*1024 + k0 + c4;
    #pragma unroll
    for (int i=0;i<16;i+=4){
      float4 f = *(const float4*)(src + i);
      tile[r][c4+i]=f.x; tile[r][c4+i+1]=f.y; tile[r][c4+i+2]=f.z; tile[r][c4+i+3]=f.w;
    }
  } else {
    #pragma unroll
    for (int i=0;i<16;++i) tile[r][c4+i]=0.f;
  }
  __syncthreads();
  int vv = tid & 63; int kkb = (tid >> 6) * 16;
  #pragma unroll
  for (int i=0;i<16;++i){
    int kk = kkb + i;
    wt[(size_t)(k0+kk)*VP + v0 + vv] = to_bf16(tile[vv][kk]);
  }
}

// wv[k] = sum_v Wo[v][k]*Wd[v]; wv[1024]=bo.Wd; wv[1025]=sum Wd
__global__ void __launch_bounds__(256)
k_wv(const float* __restrict__ Wo, const float* __restrict__ bo,
     const float* __restrict__ Wd, float* __restrict__ wv){
  __shared__ float wds[128];
  __shared__ float red[256];
  int tid = threadIdx.x;
  int v0 = blockIdx.x*128;
  float pbo=0.f, pwd=0.f;
  if (tid < 128){
    int v = v0 + tid;
    float wd = (v<VV)? Wd[v] : 0.f;
    wds[tid] = wd;
    pbo = wd * ((v<VV)? bo[v] : 0.f);
    pwd = wd;
  }
  __syncthreads();
  float4 acc = {0,0,0,0};
  int nmax = (v0 + 128 <= VV) ? 128 : (VV - v0);
  for (int i=0;i<nmax;++i){
    float wd = wds[i];
    float4 w4 = *(const float4*)(Wo + (size_t)(v0+i)*1024 + tid*4);
    acc.x += wd*w4.x; acc.y += wd*w4.y; acc.z += wd*w4.z; acc.w += wd*w4.w;
  }
  atomicAdd(&wv[tid*4+0], acc.x);
  atomicAdd(&wv[tid*4+1], acc.y);
  atomicAdd(&wv[tid*4+2], acc.z);
  atomicAdd(&wv[tid*4+3], acc.w);
  red[tid] = pbo; __syncthreads();
  for (int s=128; s; s>>=1){ if (tid<s) red[tid]+=red[tid+s]; __syncthreads(); }
  if (tid==0) atomicAdd(&wv[1024], red[0]);
  __syncthreads();
  red[tid] = pwd; __syncthreads();
  for (int s=128; s; s>>=1){ if (tid<s) red[tid]+=red[tid+s]; __syncthreads(); }
  if (tid==0) atomicAdd(&wv[1025], red[0]);
}

// one GRU step: hout[b*512+k]; hin/hout bases passed (row layout b*512+k)
__global__ void k_grustep(const float* __restrict__ W_hh, const float* __restrict__ b_hh,
                          const float* __restrict__ hin, float* __restrict__ hout,
                          const float* __restrict__ gi_all, int t){
  int wid  = blockIdx.x*4 + (threadIdx.x>>6);  // B*H waves
  int lane = threadIdx.x & 63;
  int b = wid >> 9; int k = wid & 511;
  const float* h  = hin + b*HH;
  const float* wr = W_hh + k*HH;
  const float* wz = W_hh + (HH + k)*HH;
  const float* wn = W_hh + (2*HH + k)*HH;
  float pr=0.f, pz=0.f, pn=0.f;
  for (int kk=lane; kk<HH; kk+=64){
    float hv = h[kk];
    pr += hv*wr[kk]; pz += hv*wz[kk]; pn += hv*wn[kk];
  }
  for (int off=32; off; off>>=1){
    pr += __shfl_xor(pr,off); pz += __shfl_xor(pz,off); pn += __shfl_xor(pn,off);
  }
  if (lane == 0){
    const float* gi = gi_all + (b*TT + t)*G3;
    float r = sigm(gi[k]      + pr + b_hh[k]);
    float z = sigm(gi[HH+k]   + pz + b_hh[HH+k]);
    float n = tanhf(gi[2*HH+k] + r*(pn + b_hh[2*HH+k]));
    hout[b*HH+k] = (1.f-z)*n + z*h[k];
  }
}

// Lh + bo -> out rows (h-half of logits, fp32 weights)
__global__ void __launch_bounds__(256)
k_lh(const float* __restrict__ Wo, const float* __restrict__ bo,
     const float* __restrict__ ws, float* __restrict__ out){
  __shared__ float hs_[512*36];
  int tid = threadIdx.x;
  int tg = blockIdx.y;            // 16 groups of 32 rows
  const float* hall = ws + OFF_HALL;
  for (int e = tid; e < 32*512; e += 256){
    int r = e >> 9, k = e & 511;
    hs_[k*36 + r] = hall[(size_t)(tg*32 + r)*512 + k];
  }
  __syncthreads();
  int v = blockIdx.x*256 + tid;
  if (v >= VV) return;
  float4 acc4[8];
  #pragma unroll
  for (int j=0;j<8;++j) acc4[j] = make_float4(0.f,0.f,0.f,0.f);
  const float* wrow = Wo + (size_t)v*1024 + 512;
  const float4* hp4 = (const float4*)hs_;
  for (int k=0;k<512;++k){
    float w = wrow[k];
    #pragma unroll
    for (int j=0;j<8;++j){
      float4 hv = hp4[k*9 + j];
      acc4[j].x += w*hv.x; acc4[j].y += w*hv.y; acc4[j].z += w*hv.z; acc4[j].w += w*hv.w;
    }
  }
  float bv = bo[v];
  #pragma unroll
  for (int j=0;j<8;++j){
    float a[4] = {acc4[j].x, acc4[j].y, acc4[j].z, acc4[j].w};
    #pragma unroll
    for (int i=0;i<4;++i){
      int rg = tg*32 + j*4 + i;
      int t = rg >> 3, b = rg & 7;
      out[(size_t)(b*TT+t)*VV + v] = a[i] + bv;
    }
  }
}

// hs[row]=h.Ws ; hwv[row]=h.wv_h
__global__ void k_hdots(const float* __restrict__ Ws, float* __restrict__ ws){
  int wid  = blockIdx.x*4 + (threadIdx.x>>6);  // 1024 waves
  int lane = threadIdx.x & 63;
  int row = wid >> 1, which = wid & 1;
  const float* h = ws + OFF_HALL + row*HH;
  const float* src = which ? (ws + OFF_WV + 512) : Ws;
  float acc = 0.f;
  for (int k=lane; k<HH; k+=64) acc += h[k]*src[k];
  for (int off=32; off; off>>=1) acc += __shfl_xor(acc, off);
  if (lane == 0) (which ? ws+OFF_HWV : ws+OFF_HS)[row] = acc;
}

// p[row][u] = masked softmax of hu_row . u_output[b,u,:]
__global__ void k_p(const float* __restrict__ u_output, const int* __restrict__ u_len,
                    float* __restrict__ ws){
  int row = blockIdx.x;          // t*8+b
  int b = row & 7;
  int tid = threadIdx.x;
  __shared__ float su_s[UU];
  {
    int u = tid >> 3, l8 = tid & 7;
    const float* hu = ws + OFF_HU + row*512;
    const float* uo = u_output + (size_t)(b*UU + u)*MM;
    float acc = 0.f;
    for (int m=l8; m<MM; m+=8) acc += hu[m]*uo[m];
    acc += __shfl_xor(acc,1); acc += __shfl_xor(acc,2); acc += __shfl_xor(acc,4);
    if (l8 == 0) su_s[u] = acc;
  }
  __syncthreads();
  if (tid < 32){
    int ul = u_len[b];
    float sv = su_s[tid];
    bool valid = tid < ul;
    float mv = valid ? sv : -1e30f;
    for (int off=16; off; off>>=1) mv = fmaxf(mv, __shfl_xor(mv, off));
    float e = valid ? __expf(sv - mv) : 0.f;
    float ssum = e;
    for (int off=16; off; off>>=1) ssum += __shfl_xor(ssum, off);
    ws[OFF_P + row*UU + tid] = e/ssum;
  }
}

// segment softmax of sw row (in place -> pw)
__global__ void k_pw(const int* __restrict__ word2utt, const int* __restrict__ w_len,
                     float* __restrict__ ws){
  int row = blockIdx.x;  // t*8+b
  int b = row & 7;
  int tid = threadIdx.x;
  __shared__ float sarr[WW];
  __shared__ int   seg[WW];
  __shared__ float marr[UU], darr[UU];
  int wl = w_len[b];
  float* swrow = ws + OFF_SW + row*WW;
  for (int w=tid; w<WW; w+=256){ sarr[w] = swrow[w]; seg[w] = word2utt[b*WW+w]; }
  __syncthreads();
  {
    int g = tid>>3, l8 = tid&7;
    float mv = -1e30f;
    for (int w=l8; w<wl; w+=8) if (seg[w]==g) mv = fmaxf(mv, sarr[w]);
    mv = fmaxf(mv, __shfl_xor(mv,1)); mv = fmaxf(mv, __shfl_xor(mv,2)); mv = fmaxf(mv, __shfl_xor(mv,4));
    float d = 0.f;
    for (int w=l8; w<wl; w+=8) if (seg[w]==g) d += __expf(sarr[w]-mv);
    d += __shfl_xor(d,1); d += __shfl_xor(d,2); d += __shfl_xor(d,4);
    if (l8 == 0){ marr[g]=mv; darr[g]=d; }
  }
  __syncthreads();
  for (int w=tid; w<WW; w+=256){
    float val = 0.f;
    if (w < wl){ int u = seg[w]; val = __expf(sarr[w]-marr[u])/darr[u]; }
    swrow[w] = val;
  }
}

// C[row][u][m] (bf16) = sum_{w in seg u} pw*w_out[b][w][m];  E[row][u] = C_row_u . wv_c
__global__ void __launch_bounds__(256)
k_C(const float* __restrict__ w_output, const int* __restrict__ w_len,
    const int* __restrict__ u_len, const int* __restrict__ word2utt,
    float* __restrict__ ws){
  int row = blockIdx.x;  // t*8+b
  int b = row & 7;
  int tid = threadIdx.x;
  __shared__ float pws[WW];
  __shared__ int   seg[WW];
  __shared__ int   st[UU], en[UU];
  __shared__ float wvs[512];
  __shared__ float red4[8];
  int wl = w_len[b], ul = u_len[b];
  const float* pwrow = ws + OFF_SW + row*WW;
  for (int w=tid; w<WW; w+=256){ pws[w] = pwrow[w]; seg[w] = word2utt[b*WW+w]; }
  for (int m=tid; m<512; m+=256) wvs[m] = ws[OFF_WV + m];
  if (tid < UU){ st[tid]=0; en[tid]=0; }
  __syncthreads();
  for (int w=tid; w<wl; w+=256){
    int s = seg[w];
    if (w==0 || seg[w-1]!=s) st[s]=w;
    if (w==wl-1 || seg[w+1]!=s) en[s]=w+1;
  }
  __syncthreads();
  ushort_t* Cu = (ushort_t*)(ws + OFF_C);
  int m0 = tid, m1 = tid + 256;
  int lane = tid & 63, wvi = tid >> 6;
  for (int u=0; u<UU; ++u){
    float acc0=0.f, acc1=0.f;
    if (u < ul){
      int s = st[u], e = en[u];
      for (int w=s; w<e; ++w){
        float p = pws[w];
        const float* wo = w_output + ((size_t)(b*WW+w))*MM;
        acc0 += p*wo[m0];
        acc1 += p*wo[m1];
      }
    }
    size_t cbase = ((size_t)row*UU + u)*512;
    Cu[cbase + m0] = to_bf16(acc0);
    Cu[cbase + m1] = to_bf16(acc1);
    // e reduction
    float part = acc0*wvs[m0] + acc1*wvs[m1];
    for (int off=32; off; off>>=1) part += __shfl_xor(part, off);
    if (lane == 0) red4[wvi] = part;
    __syncthreads();
    if (tid == 0) ws[OFF_E + row*UU + u] = red4[0]+red4[1]+red4[2]+red4[3];
    __syncthreads();
  }
}

// ---------------- per-step serial ----------------

// block per b: lse(t-1) from partials, gamma, su mix, ctx = su.C, q = su.E
__global__ void k_tiny(const int* __restrict__ u_len, const float* __restrict__ bs,
                       float* __restrict__ ws, float* __restrict__ out, int t){
  int b = blockIdx.x;
  int tid = threadIdx.x;
  int row = t*8 + b;
  __shared__ float sm[256], ss[256];
  __shared__ float suL[UU];
  __shared__ float gamma_s, lse_s;
  if (t > 0){
    float m = -1e30f, s = 0.f;
    if (tid < NLB){ m = ws[OFF_PART + tid*16 + b*2]; s = ws[OFF_PART + tid*16 + b*2 + 1]; }
    sm[tid]=m; ss[tid]=s; __syncthreads();
    for (int stp=128; stp; stp>>=1){
      if (tid < stp){
        float m1 = sm[tid], s1 = ss[tid];
        float m2 = sm[tid+stp], s2 = ss[tid+stp];
        float mm = fmaxf(m1, m2);
        ss[tid] = s1*__expf(m1-mm) + s2*__expf(m2-mm);
        sm[tid] = mm;
      }
      __syncthreads();
    }
    if (tid == 0){
      float lse = sm[0] + logf(ss[0]);
      lse_s = lse;
      ws[OFF_LSE + (t-1)*8 + b] = lse;
    }
    __syncthreads();
  }
  if (tid == 0){
    float pd = 0.f;
    if (t > 0){
      pd = ws[OFF_QBUF + b] + ws[OFF_HWV + (t-1)*8 + b]
         + ws[OFF_WV + 1024] - lse_s * ws[OFF_WV + 1025];
    }
    gamma_s = sigm(pd + ws[OFF_WY + b*TT + t] + ws[OFF_HS + row] + bs[0]);
  }
  __syncthreads();
  if (tid < 32){
    float g = gamma_s;
    float p = ws[OFF_P + row*UU + tid];
    float eu = (t > 0) ? ws[OFF_SUBUF + b*UU + tid] : 0.f;
    float mix = (1.f-g)*p + g*eu;
    float s2 = mix;
    for (int off=16; off; off>>=1) s2 += __shfl_xor(s2, off);
    float su = mix / s2;
    ws[OFF_SUBUF + b*UU + tid] = su;
    out[SU_OFF + (b*TT + t)*UU + tid] = su;
    suL[tid] = su;
    float qp = su * ws[OFF_E + row*UU + tid];
    for (int off=16; off; off>>=1) qp += __shfl_xor(qp, off);
    if (tid == 0) ws[OFF_QBUF + b] = qp;
  }
  __syncthreads();
  const ushort_t* Cu = (const ushort_t*)(ws + OFF_C);
  int m0 = tid, m1 = tid + 256;
  float a0=0.f, a1=0.f;
  #pragma unroll
  for (int u=0; u<UU; ++u){
    float su = suL[u];
    size_t cbase = ((size_t)row*UU + u)*512;
    a0 += su * from_bf16(Cu[cbase + m0]);
    a1 += su * from_bf16(Cu[cbase + m1]);
  }
  ws[OFF_CTXT + m0*8 + b] = a0;
  ws[OFF_CTXT + m1*8 + b] = a1;
}

// ctx-half logits: out += ctx.WoC (out pre-holds Lh+bo); emit per-block (m,s) partials
__global__ void __launch_bounds__(256)
k_big(const ushort_t* __restrict__ wt, const float* __restrict__ ws_c,
      float* __restrict__ out, float* __restrict__ part, int t){
  int tid = threadIdx.x;
  int kq = tid >> 6, vl = tid & 63;
  int v0 = blockIdx.x * 128;
  int v = v0 + 2*vl;
  float acc0[8] = {0,0,0,0,0,0,0,0};
  float acc1[8] = {0,0,0,0,0,0,0,0};
  const float* cp = ws_c + kq*128*8;   // ctxT[k][b]
  const ushort_t* wp = wt + (size_t)(kq*128)*VP + v;
  #pragma unroll 8
  for (int k=0;k<128;++k){
    uint_t w2 = *(const uint_t*)(wp); wp += VP;
    float w0 = __uint_as_float((w2 & 0xffffu) << 16);
    float w1 = __uint_as_float((w2 >> 16) << 16);
    float c[8];
    #pragma unroll
    for (int b=0;b<8;++b) c[b] = cp[k*8+b];
    #pragma unroll
    for (int b=0;b<8;++b){ acc0[b] += w0*c[b]; acc1[b] += w1*c[b]; }
  }
  __shared__ float partial[4][128][8];
  #pragma unroll
  for (int b=0;b<8;++b){
    partial[kq][2*vl][b]   = acc0[b];
    partial[kq][2*vl+1][b] = acc1[b];
  }
  __syncthreads();
  __shared__ float fin[128][8];
  for (int o = tid; o < 1024; o += 256){
    int vv = o >> 3, b = o & 7;
    int gv = v0 + vv;
    float s = partial[0][vv][b]+partial[1][vv][b]+partial[2][vv][b]+partial[3][vv][b];
    float logit = -1e30f;
    if (gv < VV){
      size_t oidx = (size_t)(b*TT+t)*VV + gv;
      logit = s + out[oidx];
      out[oidx] = logit;
    }
    fin[vv][b] = logit;
  }
  __syncthreads();
  int b = tid >> 5;
  int l = tid & 31;
  float m = -1e30f;
  for (int vv=l; vv<128; vv+=32) m = fmaxf(m, fin[vv][b]);
  for (int off=16; off; off>>=1) m = fmaxf(m, __shfl_xor(m, off));
  float s = 0.f;
  for (int vv=l; vv<128; vv+=32) s += __expf(fin[vv][b] - m);
  for (int off=16; off; off>>=1) s += __shfl_xor(s, off);
  if (l == 0){ part[blockIdx.x*16 + b*2] = m; part[blockIdx.x*16 + b*2 + 1] = s; }
}

// ---------------- finals ----------------

__global__ void k_lsefin(float* __restrict__ ws){
  int b = blockIdx.x;
  int tid = threadIdx.x;
  __shared__ float sm[256], ss[256];
  float m = -1e30f, s = 0.f;
  if (tid < NLB){ m = ws[OFF_PART + tid*16 + b*2]; s = ws[OFF_PART + tid*16 + b*2 + 1]; }
  sm[tid]=m; ss[tid]=s; __syncthreads();
  for (int stp=128; stp; stp>>=1){
    if (tid < stp){
      float m1 = sm[tid], s1 = ss[tid];
      float m2 = sm[tid+stp], s2 = ss[tid+stp];
      float mm = fmaxf(m1, m2);
      ss[tid] = s1*__expf(m1-mm) + s2*__expf(m2-mm);
      sm[tid] = mm;
    }
    __syncthreads();
  }
  if (tid == 0) ws[OFF_LSE + 63*8 + b] = sm[0] + logf(ss[0]);
}

__global__ void k_sub2(const float* __restrict__ ws, float* __restrict__ out){
  int v = blockIdx.x*256 + threadIdx.x;
  int tb = blockIdx.y;
  int t = tb >> 3, b = tb & 7;
  if (v < VV) out[(size_t)(b*TT+t)*VV + v] -= ws[OFF_LSE + tb];
}

__global__ void k_suw2(const int* __restrict__ word2utt, const float* __restrict__ ws,
                       float* __restrict__ out){
  int row = blockIdx.x;   // t*8+b
  int t = row >> 3, b = row & 7;
  int tid = threadIdx.x;
  for (int w=tid; w<WW; w+=256){
    int seg = word2utt[b*WW + w];
    float su = out[SU_OFF + (b*TT+t)*UU + seg];
    float pw = ws[OFF_SW + row*WW + w];
    out[SUW_OFF + (b*TT+t)*WW + w] = su*pw;
  }
}

extern "C" void kernel_launch(void* const* d_in, const int* in_sizes, int n_in,
                              void* d_out, int out_size, void* d_ws, size_t ws_size,
                              hipStream_t stream) {
  const int*   target   = (const int*)d_in[0];
  const float* u_output = (const float*)d_in[1];
  const float* w_output = (const float*)d_in[2];
  const int*   u_len    = (const int*)d_in[3];
  const int*   w_len    = (const int*)d_in[4];
  const int*   word2utt = (const int*)d_in[5];
  const float* emb      = (const float*)d_in[6];
  const float* W_ih     = (const float*)d_in[7];
  const float* W_hh     = (const float*)d_in[8];
  const float* b_ih     = (const float*)d_in[9];
  const float* b_hh     = (const float*)d_in[10];
  const float* Wu       = (const float*)d_in[11];
  const float* Ww       = (const float*)d_in[13];
  const float* Wo       = (const float*)d_in[15];
  const float* bo       = (const float*)d_in[16];
  const float* Wd       = (const float*)d_in[17];
  const float* Wy       = (const float*)d_in[18];
  const float* Ws       = (const float*)d_in[19];
  const float* bs       = (const float*)d_in[20];
  float* out = (float*)d_out;
  float* ws  = (float*)d_ws;
  ushort_t* wotc = (ushort_t*)(ws + OFF_WOTC);

  // --- precompute (batched) ---
  hipLaunchKernelGGL(k_gather_y, dim3(512), dim3(256), 0, stream, target, emb, ws);
  // gi = y_all @ W_ih^T + b_ih  [512,1536]
  hipLaunchKernelGGL((k_gemm_b<1>), dim3(24,8,1), dim3(256), 0, stream,
                     ws+OFF_YALL, 256, 0, W_ih, 256, 0, b_ih, ws+OFF_GI, 1536, 0, 256);
  hipLaunchKernelGGL(k_wy, dim3(128), dim3(256), 0, stream, Wy, ws);
  hipLaunchKernelGGL(k_h0, dim3(16), dim3(256), 0, stream, u_output, u_len, ws);
  hipLaunchKernelGGL(k_woTc, dim3(VP/64, 8), dim3(256), 0, stream, Wo, wotc);
  hipMemsetAsync(ws + OFF_WV, 0, 1536*sizeof(float), stream);
  hipLaunchKernelGGL(k_wv, dim3(NLB), dim3(256), 0, stream, Wo, bo, Wd, ws+OFF_WV);

  // --- GRU hidden chain (only true sequential part of the recurrence) ---
  for (int t=0; t<TT; ++t){
    const float* hin = (t==0) ? (ws+OFF_H0) : (ws+OFF_HALL + (size_t)(t-1)*4096);
    float* hout = ws + OFF_HALL + (size_t)t*4096;
    hipLaunchKernelGGL(k_grustep, dim3(1024), dim3(256), 0, stream,
                       W_hh, b_hh, hin, hout, ws+OFF_GI, t);
  }

  // --- batched post-h precompute ---
  hipLaunchKernelGGL(k_lh, dim3(118, 16), dim3(256), 0, stream, Wo, bo, ws, out);
  // hu = h @ Wu (NN), hw = h @ Ww (NN)
  hipLaunchKernelGGL((k_gemm_b<0>), dim3(8,8,1), dim3(256), 0, stream,
                     ws+OFF_HALL, 512, 0, Wu, 512, 0, (const float*)nullptr, ws+OFF_HU, 512, 0, 512);
  hipLaunchKernelGGL((k_gemm_b<0>), dim3(8,8,1), dim3(256), 0, stream,
                     ws+OFF_HALL, 512, 0, Ww, 512, 0, (const float*)nullptr, ws+OFF_HW, 512, 0, 512);
  hipLaunchKernelGGL(k_hdots, dim3(256), dim3(256), 0, stream, Ws, ws);
  hipLaunchKernelGGL(k_p, dim3(512), dim3(256), 0, stream, u_output, u_len, ws);
  // sw[t,b,w] = hw_row . w_output[b,w,:]  (batched NT, z=b)
  hipLaunchKernelGGL((k_gemm_b<1>), dim3(8,1,8), dim3(256), 0, stream,
                     ws+OFF_HW, 4096, 512, w_output, 512, 262144, (const float*)nullptr,
                     ws+OFF_SW, 4096, 512, 512);
  hipLaunchKernelGGL(k_pw, dim3(512), dim3(256), 0, stream, word2utt, w_len, ws);
  hipLaunchKernelGGL(k_C, dim3(512), dim3(256), 0, stream,
                     w_output, w_len, u_len, word2utt, ws);

  // --- serial decode: 2 kernels per step ---
  for (int t=0; t<TT; ++t){
    hipLaunchKernelGGL(k_tiny, dim3(8), dim3(256), 0, stream, u_len, bs, ws, out, t);
    hipLaunchKernelGGL(k_big, dim3(NLB), dim3(256), 0, stream,
                       wotc, ws+OFF_CTXT, out, ws+OFF_PART, t);
  }

  // --- batched finals ---
  hipLaunchKernelGGL(k_lsefin, dim3(8), dim3(256), 0, stream, ws);
  hipLaunchKernelGGL(k_sub2, dim3(118, 512), dim3(256), 0, stream, ws, out);
  hipLaunchKernelGGL(k_suw2, dim3(512), dim3(256), 0, stream, word2utt, ws, out);
}